// Round 1
// baseline (323.851 us; speedup 1.0000x reference)
//
#include <hip/hip_runtime.h>

// out = min_co( conv2d(x, W, SAME) ) * 2
// x (32,64,128,128) fp32, W (128,64,3,3) fp32 -> out (32,1,128,128) fp32
//
// Round 5: attack the LDS data pipe (was ~68% busy: 110k cyc A-reads +
// 61k cyc staging-write 16-way conflicts + 49k cyc shfl bpermutes per CU).
//   * 32x32x16 MFMA, 4M x 2N waves: 72 ds_read_b128/wave (was 144),
//     A duplication 2x (was 4x), B stays global (L2-resident 147 KB).
//   * staging lane remap: ci in lane bits 2-4, w-quad in bits 0-1,5 ->
//     writes hit 16 distinct banks (2-way = free) instead of 2 (16-way).
//   * epilogue: DPP row_ror min (VALU) replaces 4 of 5 shfl steps; the
//     cross-16 step is folded into the scratch pass (4 slices).
//   * wt re-laid out [co][tap][ci]: all 36 B-load offsets fit imm13.

typedef __attribute__((ext_vector_type(8)))  short short8;   // 8 x bf16
typedef __attribute__((ext_vector_type(4)))  float float4v;
typedef __attribute__((ext_vector_type(16))) float float16v;

#define CI 64
#define CO 128
#define HH 128
#define WW 128
#define WP 130

#define WT_BYTES ((size_t)9 * CO * CI * 2)   // 147,456

__device__ __forceinline__ unsigned short f2bf(float f) {
    unsigned int u = __float_as_uint(f);
    u = (u + 0x7fffu + ((u >> 16) & 1u)) >> 16;   // RNE
    return (unsigned short)u;
}

template <int CTRL>
__device__ __forceinline__ float fminror(float v) {
    int t = __builtin_amdgcn_mov_dpp(__float_as_int(v), CTRL, 0xF, 0xF, false);
    return fminf(v, __int_as_float(t));
}

// ---- prep_w: W (co,ci,3,3) fp32 -> wt[co][tap][ci] bf16 -------------------
// Layout so the K-loop's per-step B offsets (tap*64 + ks*16 elems, max
// 1120 B) fold into the 13-bit signed global-load immediate.

__global__ __launch_bounds__(256) void prep_w(
    const float* __restrict__ Wsrc, unsigned short* __restrict__ wt)
{
    int idx = blockIdx.x * 256 + threadIdx.x;          // (tap, co, ci)
    if (idx >= 9 * CO * CI) return;
    int ci  = idx & 63;
    int t   = idx >> 6;
    int co  = t & 127;
    int tap = t >> 7;
    wt[((size_t)co * 9 + tap) * CI + ci] =
        f2bf(Wsrc[((size_t)co * CI + ci) * 9 + tap]);
}

// ---- fused conv + min -----------------------------------------------------

#define LDSA_BYTES (4 * WP * CI * 2)   // 66,560 : 4 padded rows, 128 B/pixel

__global__ __launch_bounds__(512, 4) void conv_fused(
    const float* __restrict__ x,
    const unsigned short* __restrict__ wt,
    float* __restrict__ out)
{
    __shared__ __align__(16) char ldsA[LDSA_BYTES];
    __shared__ float scratch[4][256];

    const int bx   = blockIdx.x;       // output rows 2bx, 2bx+1
    const int b    = blockIdx.y;
    const int tid  = threadIdx.x;
    const int wid  = tid >> 6;
    const int lane = tid & 63;
    const int l31  = lane & 31;
    const int hi   = lane >> 5;
    const int wm   = wid & 3;          // M quarter: pixels wm*64 .. wm*64+63
    const int wn   = wid >> 2;         // co half (64 co each)
    const int n0   = wn * 64;

    // ---- zero pad columns (wp = 0, 129) of all 4 LDS rows ----
    if (tid < 64) {
        int r    = tid >> 4;
        int wp   = ((tid >> 3) & 1) ? 129 : 0;
        int slot = tid & 7;
        float4v z = {0.f, 0.f, 0.f, 0.f};
        *(float4v*)(ldsA + ((size_t)(r * WP + wp) * 128) + slot * 16) = z;
    }
    // ---- zero out-of-bounds rows (edge blocks only; wave-uniform) ----
    if (bx == 0) {                      // LDS row 0 = x row -1
        float4v z = {0.f, 0.f, 0.f, 0.f};
        for (int i = tid; i < WP * CI * 2 / 16; i += 512)
            ((float4v*)ldsA)[i] = z;
    }
    if (bx == HH / 2 - 1) {             // LDS row 3 = x row 128
        float4v z = {0.f, 0.f, 0.f, 0.f};
        for (int i = tid; i < WP * CI * 2 / 16; i += 512)
            ((float4v*)(ldsA + 3 * WP * 128))[i] = z;
    }

    // ---- stage: fp32 -> bf16 transpose into LDS (conflict-free writes) ----
    // lane bits: 0-1 + hi -> w-quad low, 2-4 -> ci pair; wave: wm -> ci hi,
    // wn -> w-quad bit3; k: bit0 -> w-quad bit4, bits1-2 -> LDS row r.
    // Per 32-lane phase the write banks = f(lane bits 0,2,3,4): 16 distinct,
    // 2-way aliased (free), vs 2 banks (16-way) before.
    {
        const int cpl = (lane >> 2) & 7;
        const int qlo = (lane & 3) + 4 * hi;          // 0..7
        const int ci0 = 2 * (cpl + 8 * wm);           // 0..62
        #pragma unroll
        for (int k = 0; k < 8; ++k) {
            const int r = k >> 1;
            const int Q = qlo + 8 * (wn + 2 * (k & 1));   // 0..31
            const int h = 2 * bx - 1 + r;
            if (h >= 0 && h < HH) {
                const float* p0 = x + (((size_t)b * CI + ci0) * HH + h) * WW + Q * 4;
                float4v a0 = *(const float4v*)p0;
                float4v a1 = *(const float4v*)(p0 + (size_t)HH * WW);
                #pragma unroll
                for (int e = 0; e < 4; ++e) {
                    const int wp   = Q * 4 + e + 1;           // 1..128
                    const int slot = (ci0 >> 3) ^ (wp & 7);   // 16B-slot swizzle
                    unsigned int pack = (unsigned int)f2bf(a0[e])
                                      | ((unsigned int)f2bf(a1[e]) << 16);
                    *(unsigned int*)(ldsA + (size_t)(r * WP + wp) * 128
                                     + slot * 16 + (ci0 & 7) * 2) = pack;
                }
            }
        }
    }
    __syncthreads();

    // ---- K-loop: 9 taps x 4 ksteps, 32x32x16 MFMA, 2x2 frags/wave ----
    // A frag: row = l31 (pixel), k = hi*8 + e.  B frag: col = l31 (co).
    const int prow = wm >> 1;
    const int wb2  = (wm & 1) * 64;
    int ab[2][3], hk[2][3];
    #pragma unroll
    for (int mt = 0; mt < 2; ++mt)
        #pragma unroll
        for (int dw = 0; dw < 3; ++dw) {
            const int wp = wb2 + mt * 32 + l31 + dw;   // padded col 0..129
            ab[mt][dw] = (prow * WP + wp) * 128;
            hk[mt][dw] = (hi ^ (wp & 7)) << 4;
        }
    const unsigned short* wb0 = wt + (size_t)(n0 + l31) * (9 * CI) + hi * 8;
    const unsigned short* wb1 = wb0 + (size_t)32 * 9 * CI;

    float16v acc00, acc01, acc10, acc11;
    #pragma unroll
    for (int i = 0; i < 16; ++i) {
        acc00[i] = 0.f; acc01[i] = 0.f; acc10[i] = 0.f; acc11[i] = 0.f;
    }

// slot16 = ((ks*2 + hi) ^ key)<<4 == (ks<<5) ^ ((hi^key)<<4)  (pure shifts)
#define A_ADDR(mt_, tap_, ks_) \
    (ab[mt_][(tap_) % 3] + ((tap_) / 3) * (WP * 128) \
     + (((ks_) << 5) ^ hk[mt_][(tap_) % 3]))

#define LOAD_STEP(A0_, A1_, B0_, B1_, tap_, ks_) do {                     \
    A0_ = *(const short8*)(ldsA + A_ADDR(0, tap_, ks_));                  \
    A1_ = *(const short8*)(ldsA + A_ADDR(1, tap_, ks_));                  \
    B0_ = *(const short8*)(wb0 + (tap_) * CI + (ks_) * 16);               \
    B1_ = *(const short8*)(wb1 + (tap_) * CI + (ks_) * 16);               \
} while (0)

    short8 a0c, a1c, b0c, b1c, a0n, a1n, b0n, b1n;
    LOAD_STEP(a0c, a1c, b0c, b1c, 0, 0);

    #pragma unroll
    for (int s = 0; s < 36; ++s) {
        if (s < 35) {
            const int sn = s + 1;
            LOAD_STEP(a0n, a1n, b0n, b1n, sn >> 2, sn & 3);
        }
        acc00 = __builtin_amdgcn_mfma_f32_32x32x16_bf16(a0c, b0c, acc00, 0, 0, 0);
        acc01 = __builtin_amdgcn_mfma_f32_32x32x16_bf16(a0c, b1c, acc01, 0, 0, 0);
        acc10 = __builtin_amdgcn_mfma_f32_32x32x16_bf16(a1c, b0c, acc10, 0, 0, 0);
        acc11 = __builtin_amdgcn_mfma_f32_32x32x16_bf16(a1c, b1c, acc11, 0, 0, 0);
        a0c = a0n; a1c = a1n; b0c = b0n; b1c = b1n;
    }
#undef LOAD_STEP
#undef A_ADDR

    // ---- epilogue: min over co ----
    // D: col = l31 (co), row = (r&3) + 8*(r>>2) + 4*hi (pixel within mt*32).
    // 1) min across nt; 2) min across the 16-lane row via DPP row_ror
    //    (VALU, zero LDS); 3) cross-16 combine folded into the scratch pass.
    float pm0[16], pm1[16];
    #pragma unroll
    for (int r = 0; r < 16; ++r) {
        pm0[r] = fminf(acc00[r], acc01[r]);
        pm1[r] = fminf(acc10[r], acc11[r]);
    }
    #pragma unroll
    for (int r = 0; r < 16; ++r) {
        pm0[r] = fminror<0x128>(pm0[r]);   // ror 8
        pm0[r] = fminror<0x124>(pm0[r]);   // ror 4
        pm0[r] = fminror<0x122>(pm0[r]);   // ror 2
        pm0[r] = fminror<0x121>(pm0[r]);   // ror 1
        pm1[r] = fminror<0x128>(pm1[r]);
        pm1[r] = fminror<0x124>(pm1[r]);
        pm1[r] = fminror<0x122>(pm1[r]);
        pm1[r] = fminror<0x121>(pm1[r]);
    }
    if ((l31 & 15) == 0) {
        const int g = wn * 2 + (l31 >> 4);   // which co-16 slice
        #pragma unroll
        for (int r = 0; r < 16; ++r) {
            const int row = (r & 3) + 8 * (r >> 2) + 4 * hi;
            scratch[g][wm * 64 + row]      = pm0[r];
            scratch[g][wm * 64 + 32 + row] = pm1[r];
        }
    }
    __syncthreads();
    if (tid < 256) {
        float v = fminf(fminf(scratch[0][tid], scratch[1][tid]),
                        fminf(scratch[2][tid], scratch[3][tid])) * 2.0f;
        out[((size_t)b * HH + 2 * bx + (tid >> 7)) * WW + (tid & 127)] = v;
    }
}

// ---------------- fallback (round-1 direct conv) ----------------

#define COT 16
__global__ __launch_bounds__(256) void conv_min_fallback(
    const float* __restrict__ x, const float* __restrict__ Wt,
    float* __restrict__ out)
{
    const int b  = blockIdx.y;
    const int h  = blockIdx.x * 2 + (threadIdx.x >> 7);
    const int w  = threadIdx.x & 127;
    const bool r0 = h > 0, r2 = h < HH - 1, c0 = w > 0, c2 = w < WW - 1;
    const float* xb = x + (size_t)b * CI * HH * WW;
    float vmin = 3.4e38f;
    for (int cb = 0; cb < CO; cb += COT) {
        float acc[COT];
        #pragma unroll
        for (int u = 0; u < COT; ++u) acc[u] = 0.0f;
        #pragma unroll 1
        for (int ci = 0; ci < CI; ++ci) {
            const float* xp = xb + ((size_t)ci * HH + h) * WW + w;
            float xv[9];
            xv[0] = (r0 && c0) ? xp[-WW - 1] : 0.0f;
            xv[1] =  r0        ? xp[-WW    ] : 0.0f;
            xv[2] = (r0 && c2) ? xp[-WW + 1] : 0.0f;
            xv[3] =        c0  ? xp[-1     ] : 0.0f;
            xv[4] =              xp[0      ];
            xv[5] =        c2  ? xp[1      ] : 0.0f;
            xv[6] = (r2 && c0) ? xp[ WW - 1] : 0.0f;
            xv[7] =  r2        ? xp[ WW    ] : 0.0f;
            xv[8] = (r2 && c2) ? xp[ WW + 1] : 0.0f;
            #pragma unroll
            for (int u = 0; u < COT; ++u) {
                const float* wp = Wt + ((size_t)(cb + u) * CI + ci) * 9;
                acc[u] += wp[0]*xv[0] + wp[1]*xv[1] + wp[2]*xv[2]
                        + wp[3]*xv[3] + wp[4]*xv[4] + wp[5]*xv[5]
                        + wp[6]*xv[6] + wp[7]*xv[7] + wp[8]*xv[8];
            }
        }
        #pragma unroll
        for (int u = 0; u < COT; ++u) vmin = fminf(vmin, acc[u]);
    }
    out[((size_t)b * HH + h) * WW + w] = vmin * 2.0f;
}

// ---------------- launch ----------------

extern "C" void kernel_launch(void* const* d_in, const int* in_sizes, int n_in,
                              void* d_out, int out_size, void* d_ws, size_t ws_size,
                              hipStream_t stream) {
    const float* x  = (const float*)d_in[0];   // (32,64,128,128)
    const float* Ws = (const float*)d_in[1];   // (128,64,3,3)
    float* out = (float*)d_out;                // (32,1,128,128)

    if (ws_size < WT_BYTES) {
        dim3 grid(HH / 2, 32);
        conv_min_fallback<<<grid, 256, 0, stream>>>(x, Ws, out);
        return;
    }

    unsigned short* wt = (unsigned short*)d_ws;

    prep_w<<<(9 * CO * CI + 255) / 256, 256, 0, stream>>>(Ws, wt);
    conv_fused<<<dim3(HH / 2, 32), 512, 0, stream>>>(x, wt, out);
}

// Round 2
// 257.526 us; speedup vs baseline: 1.2575x; 1.2575x over previous
//
#include <hip/hip_runtime.h>

// out = min_co( conv2d(x, W, SAME) ) * 2
// x (32,64,128,128) fp32, W (128,64,3,3) fp32 -> out (32,1,128,128) fp32
//
// Round 6: hybrid of R4 (best, 139 us) + R5's verified wins.
//   K-loop: back to 16x16x32 MFMA, 8M x 2N frags/wave, 16 MFMAs per
//     B-prefetch wait (~78 cyc cover vs R5's 32 -> util 23% vs 16%).
//     Register ceiling (128/wave for 2 blocks/CU) forbids deeper prefetch;
//     cover must come from MFMA cluster size.
//   Staging: R5's conflict-free lane remap (write banks 16-distinct,
//     2-way free; was 16-way). Conflicts 1.56e7 -> 5.8e6 verified.
//   Epilogue: R5's DPP row_ror min (VALU pipe, zero LDS) adapted to the
//     16x16 D-layout (co = lane&15 -> reduce within 16-lane rows).
//   B addressing: wt[co][tap][ci] so all 18 step offsets fold into imm13
//     (zero per-iter address VALU); s_setprio(1) around MFMA cluster.

typedef __attribute__((ext_vector_type(8)))  short short8;   // 8 x bf16
typedef __attribute__((ext_vector_type(4)))  float float4v;

#define CI 64
#define CO 128
#define HH 128
#define WW 128
#define WP 130

#define WT_BYTES ((size_t)9 * CO * CI * 2)   // 147,456

__device__ __forceinline__ unsigned short f2bf(float f) {
    unsigned int u = __float_as_uint(f);
    u = (u + 0x7fffu + ((u >> 16) & 1u)) >> 16;   // RNE
    return (unsigned short)u;
}

template <int CTRL>
__device__ __forceinline__ float fminror(float v) {
    int t = __builtin_amdgcn_mov_dpp(__float_as_int(v), CTRL, 0xF, 0xF, false);
    return fminf(v, __int_as_float(t));
}

// ---- prep_w: W (co,ci,3,3) fp32 -> wt[co][tap][ci] bf16 -------------------

__global__ __launch_bounds__(256) void prep_w(
    const float* __restrict__ Wsrc, unsigned short* __restrict__ wt)
{
    int idx = blockIdx.x * 256 + threadIdx.x;          // (tap, co, ci)
    if (idx >= 9 * CO * CI) return;
    int ci  = idx & 63;
    int t   = idx >> 6;
    int co  = t & 127;
    int tap = t >> 7;
    wt[((size_t)co * 9 + tap) * CI + ci] =
        f2bf(Wsrc[((size_t)co * CI + ci) * 9 + tap]);
}

// ---- fused conv + min -----------------------------------------------------

#define LDSA_BYTES (4 * WP * CI * 2)   // 66,560 : 4 padded rows, 128 B/pixel

__global__ __launch_bounds__(512, 4) void conv_fused(
    const float* __restrict__ x,
    const unsigned short* __restrict__ wt,
    float* __restrict__ out)
{
    __shared__ __align__(16) char  ldsA[LDSA_BYTES];
    __shared__ float scratch[4][2][128];

    const int bx   = blockIdx.x;       // output rows 2bx, 2bx+1
    const int b    = blockIdx.y;
    const int tid  = threadIdx.x;
    const int wid  = tid >> 6;
    const int lane = tid & 63;
    const int l15  = lane & 15;
    const int quad = lane >> 4;
    const int hi   = lane >> 5;
    const int wm   = wid & 1;          // which output row of the pair
    const int wn   = wid >> 1;         // co quarter (32 co each)
    const int n0   = wn * 32;

    // ---- zero pad columns (wp = 0, 129) of all 4 LDS rows ----
    if (tid < 64) {
        int r    = tid >> 4;
        int wp   = ((tid >> 3) & 1) ? 129 : 0;
        int slot = tid & 7;
        float4v z = {0.f, 0.f, 0.f, 0.f};
        *(float4v*)(ldsA + ((size_t)(r * WP + wp) * 128) + slot * 16) = z;
    }
    // ---- zero out-of-bounds rows (edge blocks only; wave-uniform) ----
    if (bx == 0) {                      // LDS row 0 = x row -1
        float4v z = {0.f, 0.f, 0.f, 0.f};
        for (int i = tid; i < WP * CI * 2 / 16; i += 512)
            ((float4v*)ldsA)[i] = z;
    }
    if (bx == HH / 2 - 1) {             // LDS row 3 = x row 128
        float4v z = {0.f, 0.f, 0.f, 0.f};
        for (int i = tid; i < WP * CI * 2 / 16; i += 512)
            ((float4v*)(ldsA + 3 * WP * 128))[i] = z;
    }

    // ---- stage: fp32 -> bf16 transpose into LDS (conflict-free writes) ----
    // R5 lane remap: ci varies in lane bits 2-4, w-quad in bits 0-1,5 ->
    // the 32-lane phase hits 16 distinct banks (2-way aliased = free).
    {
        const int sm  = wid & 3;                      // staging role, not wm
        const int sn  = wid >> 2;
        const int cpl = (lane >> 2) & 7;
        const int qlo = (lane & 3) + 4 * hi;          // 0..7
        const int ci0 = 2 * (cpl + 8 * sm);           // 0..62
        #pragma unroll
        for (int k = 0; k < 8; ++k) {
            const int r = k >> 1;
            const int Q = qlo + 8 * (sn + 2 * (k & 1));   // 0..31
            const int h = 2 * bx - 1 + r;
            if (h >= 0 && h < HH) {
                const float* p0 = x + (((size_t)b * CI + ci0) * HH + h) * WW + Q * 4;
                float4v a0 = *(const float4v*)p0;
                float4v a1 = *(const float4v*)(p0 + (size_t)HH * WW);
                #pragma unroll
                for (int e = 0; e < 4; ++e) {
                    const int wp   = Q * 4 + e + 1;           // 1..128
                    const int slot = (ci0 >> 3) ^ (wp & 7);   // 16B-slot swizzle
                    unsigned int pack = (unsigned int)f2bf(a0[e])
                                      | ((unsigned int)f2bf(a1[e]) << 16);
                    *(unsigned int*)(ldsA + (size_t)(r * WP + wp) * 128
                                     + slot * 16 + (ci0 & 7) * 2) = pack;
                }
            }
        }
    }
    __syncthreads();

    // ---- K-loop: 9 taps x 2 kc, 16 MFMAs per B-wait, B reg-dbuf ----
    float4v acc[8][2];
    #pragma unroll
    for (int mt = 0; mt < 8; ++mt)
        #pragma unroll
        for (int nt = 0; nt < 2; ++nt)
            acc[mt][nt] = (float4v){0.f, 0.f, 0.f, 0.f};

    // wt[co][tap][ci]: lane base co = n0 + nt*16 + l15, k-slice quad*8.
    // Per-step offset tap*64 + kc*32 elems (<= 1088 B) folds into imm13.
    const unsigned short* wb0 = wt + (size_t)(n0 + l15) * (9 * CI) + quad * 8;
    const unsigned short* wb1 = wb0 + (size_t)16 * 9 * CI;

    short8 bcur[2], bnxt[2];
    bcur[0] = *(const short8*)(wb0);
    bcur[1] = *(const short8*)(wb1);

    #pragma unroll
    for (int it = 0; it < 18; ++it) {
        const int tap = it >> 1;
        const int kc  = it & 1;
        const int dh  = tap / 3;
        const int dw  = tap % 3;

        if (it < 17) {                         // prefetch next B fragments
            const int tn  = it + 1;
            const int off = (tn >> 1) * CI + (tn & 1) * 32;
            bnxt[0] = *(const short8*)(wb0 + off);
            bnxt[1] = *(const short8*)(wb1 + off);
        }

        const int key     = (dw + l15) & 7;
        const int rowbase = (wm + dh) * WP + dw + l15;
        const int sp      = ((kc * 4 + quad) ^ key) * 16;

        short8 af[8];
        #pragma unroll
        for (int mt = 0; mt < 8; ++mt)
            af[mt] = *(const short8*)(ldsA + (size_t)(rowbase + mt * 16) * 128 + sp);

        __builtin_amdgcn_s_setprio(1);
        #pragma unroll
        for (int mt = 0; mt < 8; ++mt)
            #pragma unroll
            for (int nt = 0; nt < 2; ++nt)
                acc[mt][nt] = __builtin_amdgcn_mfma_f32_16x16x32_bf16(
                    af[mt], bcur[nt], acc[mt][nt], 0, 0, 0);
        __builtin_amdgcn_s_setprio(0);

        bcur[0] = bnxt[0];
        bcur[1] = bnxt[1];
    }

    // ---- epilogue: min over co, *2 ----
    // D: co = n0 + nt*16 + l15, pixel = mt*16 + quad*4 + reg.
    // 1) fmin across nt in-reg; 2) DPP row_ror min over l15 (16-lane rows,
    //    VALU pipe, zero LDS); 3) combine 4 wn slices via scratch.
    float pm[8][4];
    #pragma unroll
    for (int mt = 0; mt < 8; ++mt)
        #pragma unroll
        for (int reg = 0; reg < 4; ++reg)
            pm[mt][reg] = fminf(acc[mt][0][reg], acc[mt][1][reg]);
    #pragma unroll
    for (int mt = 0; mt < 8; ++mt)
        #pragma unroll
        for (int reg = 0; reg < 4; ++reg) {
            pm[mt][reg] = fminror<0x128>(pm[mt][reg]);   // row_ror:8
            pm[mt][reg] = fminror<0x124>(pm[mt][reg]);   // row_ror:4
            pm[mt][reg] = fminror<0x122>(pm[mt][reg]);   // row_ror:2
            pm[mt][reg] = fminror<0x121>(pm[mt][reg]);   // row_ror:1
        }
    if (l15 == 0) {
        #pragma unroll
        for (int mt = 0; mt < 8; ++mt)
            #pragma unroll
            for (int reg = 0; reg < 4; ++reg)
                scratch[wn][wm][mt * 16 + quad * 4 + reg] = pm[mt][reg];
    }
    __syncthreads();
    if (tid < 256) {
        int r = tid >> 7, c = tid & 127;
        float v = fminf(fminf(scratch[0][r][c], scratch[1][r][c]),
                        fminf(scratch[2][r][c], scratch[3][r][c])) * 2.0f;
        out[((size_t)b * HH + 2 * bx + r) * WW + c] = v;
    }
}

// ---------------- fallback (round-1 direct conv) ----------------

#define COT 16
__global__ __launch_bounds__(256) void conv_min_fallback(
    const float* __restrict__ x, const float* __restrict__ Wt,
    float* __restrict__ out)
{
    const int b  = blockIdx.y;
    const int h  = blockIdx.x * 2 + (threadIdx.x >> 7);
    const int w  = threadIdx.x & 127;
    const bool r0 = h > 0, r2 = h < HH - 1, c0 = w > 0, c2 = w < WW - 1;
    const float* xb = x + (size_t)b * CI * HH * WW;
    float vmin = 3.4e38f;
    for (int cb = 0; cb < CO; cb += COT) {
        float acc[COT];
        #pragma unroll
        for (int u = 0; u < COT; ++u) acc[u] = 0.0f;
        #pragma unroll 1
        for (int ci = 0; ci < CI; ++ci) {
            const float* xp = xb + ((size_t)ci * HH + h) * WW + w;
            float xv[9];
            xv[0] = (r0 && c0) ? xp[-WW - 1] : 0.0f;
            xv[1] =  r0        ? xp[-WW    ] : 0.0f;
            xv[2] = (r0 && c2) ? xp[-WW + 1] : 0.0f;
            xv[3] =        c0  ? xp[-1     ] : 0.0f;
            xv[4] =              xp[0      ];
            xv[5] =        c2  ? xp[1      ] : 0.0f;
            xv[6] = (r2 && c0) ? xp[ WW - 1] : 0.0f;
            xv[7] =  r2        ? xp[ WW    ] : 0.0f;
            xv[8] = (r2 && c2) ? xp[ WW + 1] : 0.0f;
            #pragma unroll
            for (int u = 0; u < COT; ++u) {
                const float* wp = Wt + ((size_t)(cb + u) * CI + ci) * 9;
                acc[u] += wp[0]*xv[0] + wp[1]*xv[1] + wp[2]*xv[2]
                        + wp[3]*xv[3] + wp[4]*xv[4] + wp[5]*xv[5]
                        + wp[6]*xv[6] + wp[7]*xv[7] + wp[8]*xv[8];
            }
        }
        #pragma unroll
        for (int u = 0; u < COT; ++u) vmin = fminf(vmin, acc[u]);
    }
    out[((size_t)b * HH + h) * WW + w] = vmin * 2.0f;
}

// ---------------- launch ----------------

extern "C" void kernel_launch(void* const* d_in, const int* in_sizes, int n_in,
                              void* d_out, int out_size, void* d_ws, size_t ws_size,
                              hipStream_t stream) {
    const float* x  = (const float*)d_in[0];   // (32,64,128,128)
    const float* Ws = (const float*)d_in[1];   // (128,64,3,3)
    float* out = (float*)d_out;                // (32,1,128,128)

    if (ws_size < WT_BYTES) {
        dim3 grid(HH / 2, 32);
        conv_min_fallback<<<grid, 256, 0, stream>>>(x, Ws, out);
        return;
    }

    unsigned short* wt = (unsigned short*)d_ws;

    prep_w<<<(9 * CO * CI + 255) / 256, 256, 0, stream>>>(Ws, wt);
    conv_fused<<<dim3(HH / 2, 32), 512, 0, stream>>>(x, wt, out);
}